// Round 8
// baseline (573.527 us; speedup 1.0000x reference)
//
#include <hip/hip_runtime.h>
#include <stdint.h>
#include <stddef.h>

#define NQS 8192
#define NKS 8192
#define DS  256

typedef _Float16 half8 __attribute__((ext_vector_type(8)));
typedef float floatx16 __attribute__((ext_vector_type(16)));

#define MFMA32(A,B,C) __builtin_amdgcn_mfma_f32_32x32x16_f16(A,B,C,0,0,0)

// async global->LDS 16B: dest = wave-uniform base + lane*16
#define GLOAD_LDS16(gp, lp) \
  __builtin_amdgcn_global_load_lds((const __attribute__((address_space(1))) void*)(gp), \
                                   (__attribute__((address_space(3))) void*)(lp), 16, 0, 0)

// tile = 64 keys x 256 d = 16384 _Float16 elements (32 KB). POINTER ARITH IS IN
// ELEMENTS — R7 used 32768 here and read the mask region as f16 => NaN.
#define TILE_ELEMS 16384

// ---------- mask dtype detection (int32 0/1 words OR to <=1; packed bytes don't) ----------
__global__ void detect_mask(const uint32_t* __restrict__ M, uint32_t* __restrict__ flag){
  __shared__ uint32_t s[256];
  uint32_t acc = 0;
  for (int i = threadIdx.x; i < 16384; i += 256) acc |= M[i];
  s[threadIdx.x] = acc;
  __syncthreads();
  if (threadIdx.x == 0){
    uint32_t t = 0;
    for (int i = 0; i < 256; i++) t |= s[i];
    *flag = (t > 1u) ? 1u : 0u;   // 1 = bytes (uint8), 0 = int32
  }
}

// ---------- mask bit-pack, TRANSPOSED: Mp2[word(k/32)][row], coalesced both sides ----------
__global__ void pack_mask(const uint8_t* __restrict__ M8,
                          const uint32_t* __restrict__ flag,
                          uint32_t* __restrict__ Mp2){
  __shared__ uint32_t W[256];
  const int tid = threadIdx.x;
  const int rb64 = blockIdx.x * 64;
  const int r  = tid >> 2;      // 0..63 row within block
  const int ws = tid & 3;       // word sub-index
  const bool by = (*flag != 0u);
  #pragma unroll 1
  for (int j = 0; j < 64; ++j){
    const int w = j*4 + ws;     // word 0..255
    uint32_t word = 0;
    if (by){
      const uint4* p = (const uint4*)(M8 + (size_t)(rb64 + r)*8192 + w*32);
      uint4 a = p[0], b = p[1];
      uint32_t v[8] = {a.x,a.y,a.z,a.w,b.x,b.y,b.z,b.w};
      #pragma unroll
      for (int q=0;q<8;q++){
        word |= (((v[q]      ) & 0xFFu) ? 1u:0u) << (q*4+0);
        word |= (((v[q] >>  8) & 0xFFu) ? 1u:0u) << (q*4+1);
        word |= (((v[q] >> 16) & 0xFFu) ? 1u:0u) << (q*4+2);
        word |= (((v[q] >> 24)        ) ? 1u:0u) << (q*4+3);
      }
    } else {
      const uint4* p = (const uint4*)M8 + (size_t)(rb64 + r)*2048 + w*8;
      #pragma unroll
      for (int q=0;q<8;q++){
        uint4 v = p[q];
        word |= (v.x?1u:0u) << (q*4+0);
        word |= (v.y?1u:0u) << (q*4+1);
        word |= (v.z?1u:0u) << (q*4+2);
        word |= (v.w?1u:0u) << (q*4+3);
      }
    }
    W[tid] = word;
    __syncthreads();
    const int r2 = tid & 63, w2 = tid >> 6;
    Mp2[(size_t)(j*4 + w2)*NQS + rb64 + r2] = W[r2*4 + w2];
    __syncthreads();
  }
}

// ---------- K conversion: tiled layout for 32x32x16 A-operand staging ----------
// K[key][d] -> per-tile offset (((mt*16+kt)*2+t)*32 + k32)*8 + j
// tile=key>>6, mt=(key>>5)&1, k32=key&31, kt=d>>4, t=(d>>3)&1, j=d&7
__global__ void cvt_k(const float* __restrict__ K, _Float16* __restrict__ Kc){
  int gid = blockIdx.x*256 + threadIdx.x;      // 262144
  int key = gid & 8191;
  int c   = gid >> 13;                         // 0..31
  int kt = c >> 1, t = c & 1;
  const float4* s = (const float4*)(K + (size_t)key*DS + kt*16 + t*8);
  float4 x = s[0], y = s[1];
  half8 h = {(_Float16)x.x,(_Float16)x.y,(_Float16)x.z,(_Float16)x.w,
             (_Float16)y.x,(_Float16)y.y,(_Float16)y.z,(_Float16)y.w};
  int tile = key >> 6, mt = (key >> 5) & 1, k32 = key & 31;
  size_t off = (size_t)tile*TILE_ELEMS + (((mt*16 + kt)*2 + t)*32 + k32)*8;
  *(half8*)(Kc + off) = h;
}
// ---------- V conversion: tiled layout for 32x32x16 B-operand staging ----------
// V[key][d] -> per-tile offset ((((kkt*8+nt)*2+t)*32 + d32)*8 + j
// tile=key>>6, kkt=(key>>4)&3, t=(key>>3)&1, j=key&7, nt=d>>5, d32=d&31
__global__ void cvt_v(const float* __restrict__ V, _Float16* __restrict__ Vc){
  int gid = blockIdx.x*256 + threadIdx.x;      // 262144
  int d32 = gid & 31;
  int t   = (gid >> 5) & 1;
  int nt  = (gid >> 6) & 7;
  int kkt = (gid >> 9) & 3;
  int tile = gid >> 11;
  int d = nt*32 + d32;
  int kb8 = tile*64 + kkt*16 + t*8;
  half8 h;
  #pragma unroll
  for (int j=0;j<8;j++) h[j] = (_Float16)V[(size_t)(kb8 + j)*DS + d];
  *(half8*)(Vc + (size_t)gid*8) = h;
}

// ---------- main flash kernel: 32x32x16 MFMA, S^T trick, no P LDS round-trip ----------
// grid 256 = 64 row-groups(128) x 4 key-quarters, 1 block/CU (128 KB LDS).
// Wave w owns 32 queries (q = lane&31). S^T = K·Q^T: A=K (LDS), B=Q (regs).
// P exits in C-layout (q = lane&31) == PV A-operand m-index; only a shfl_xor(32)
// half-wave exchange is needed for the k(key) dimension. Fixed-max softmax.
__global__ __launch_bounds__(256, 1) void attn_fwd(
  const float* __restrict__ Qf, const _Float16* __restrict__ Kc,
  const _Float16* __restrict__ Vc, const uint32_t* __restrict__ Mp2,
  float* __restrict__ Op, float* __restrict__ Lo)
{
  __shared__ _Float16 Kls[2][16384];   // [buf] 32 KB: [(mt*16+kt)*2+t][key32][8]
  __shared__ _Float16 Vls[2][16384];   // [buf] 32 KB: [((kkt*8+nt)*2+t)][d32][8]

  const int tid  = threadIdx.x;
  const int w    = tid >> 6;
  const int lane = tid & 63;
  const int q32  = lane & 31;
  const int t    = lane >> 5;
  const int b    = blockIdx.x;
  const int g128 = b >> 2;
  const int kh   = b & 3;
  const int rowbase = (g128 << 7) + w*32;
  const int kbase   = kh << 11;
  const int tile0   = kbase >> 6;
  const int kw0     = kbase >> 5;

  const float kLog = 0.09016844005556021f;  // (1/16) * log2(e)
  const float MFIX = 6.0f;

  // Q B-frags: B[k=d16][n=q32]: n=lane&31, k=(lane>>5)*8+j
  half8 qf[16];
  {
    const float* qrow = Qf + (size_t)(rowbase + q32)*DS;
    #pragma unroll
    for (int kt=0;kt<16;kt++){
      const float4* s = (const float4*)(qrow + kt*16 + t*8);
      float4 x = s[0], y = s[1];
      qf[kt] = (half8){(_Float16)x.x,(_Float16)x.y,(_Float16)x.z,(_Float16)x.w,
                       (_Float16)y.x,(_Float16)y.y,(_Float16)y.z,(_Float16)y.w};
    }
  }

  floatx16 O[8];
  #pragma unroll
  for (int nt=0;nt<8;nt++)
    #pragma unroll
    for (int i=0;i<16;i++) O[nt][i] = 0.f;
  float lsum = 0.f;

  // ---- stage tile 0 ----
  #pragma unroll
  for (int j=0;j<8;j++){
    int c = w*8 + j;
    GLOAD_LDS16(Kc + (size_t)tile0*TILE_ELEMS + c*512 + lane*8, &Kls[0][c*512]);
    GLOAD_LDS16(Vc + (size_t)tile0*TILE_ELEMS + c*512 + lane*8, &Vls[0][c*512]);
  }
  __syncthreads();

  #pragma unroll 1
  for (int it=0; it<32; ++it){
    const int buf = it & 1;

    if (it < 31){
      const size_t tb = (size_t)(tile0 + it + 1)*TILE_ELEMS;
      #pragma unroll
      for (int j=0;j<8;j++){
        int c = w*8 + j;
        GLOAD_LDS16(Kc + tb + c*512 + lane*8, &Kls[buf^1][c*512]);
        GLOAD_LDS16(Vc + tb + c*512 + lane*8, &Vls[buf^1][c*512]);
      }
    }

    #pragma unroll
    for (int mt=0; mt<2; ++mt){
      // mask word for this lane's query, 32-key group (coalesced across lanes)
      const uint32_t mw = Mp2[(size_t)(kw0 + it*2 + mt)*NQS + rowbase + q32];

      // ---- S^T[key32][q32], two 8-deep chains ----
      floatx16 S0, S1;
      #pragma unroll
      for (int i=0;i<16;i++){ S0[i]=0.f; S1[i]=0.f; }
      #pragma unroll
      for (int kt=0;kt<8;kt++){
        half8 kA = *(const half8*)&Kls[buf][(((mt*16+kt)*2 + t)*32 + q32)*8];
        S0 = MFMA32(kA, qf[kt], S0);
      }
      #pragma unroll
      for (int kt=8;kt<16;kt++){
        half8 kA = *(const half8*)&Kls[buf][(((mt*16+kt)*2 + t)*32 + q32)*8];
        S1 = MFMA32(kA, qf[kt], S1);
      }

      // ---- p = exp2(S*kLog - MFIX) masked; pack to f16x2 by s-group ----
      uint32_t pk[4][2];
      #pragma unroll
      for (int s=0;s<4;s++){
        float pv[4];
        #pragma unroll
        for (int rr=0;rr<4;rr++){
          int i = s*4 + rr;
          int keybit = rr + 8*s + 4*t;          // key within 32-group (C-row decode)
          float e = __builtin_amdgcn_exp2f(__builtin_fmaf(S0[i]+S1[i], kLog, -MFIX));
          float p = ((mw >> keybit) & 1u) ? e : 0.f;
          lsum += p;
          pv[rr] = p;
        }
        pk[s][0] = __builtin_bit_cast(uint32_t, __builtin_amdgcn_cvt_pkrtz(pv[0], pv[1]));
        pk[s][1] = __builtin_bit_cast(uint32_t, __builtin_amdgcn_cvt_pkrtz(pv[2], pv[3]));
      }

      // ---- PV: per 16-key k-tile, assemble A-frag via half-wave exchange ----
      #pragma unroll
      for (int kt2=0; kt2<2; ++kt2){
        const int s_own  = kt2*2 + t;        // regs I keep
        const int s_send = kt2*2 + (t^1);    // regs my partner needs (I send these)
        uint32_t r0 = __shfl_xor(__builtin_bit_cast(int, pk[s_send][0]), 32);
        uint32_t r1 = __shfl_xor(__builtin_bit_cast(int, pk[s_send][1]), 32);
        uint32_t lo0 = (t==0) ? pk[s_own][0] : r0;
        uint32_t lo1 = (t==0) ? pk[s_own][1] : r1;
        uint32_t hi0 = (t==0) ? r0 : pk[s_own][0];
        uint32_t hi1 = (t==0) ? r1 : pk[s_own][1];
        uint4 u = {lo0, lo1, hi0, hi1};
        half8 pa = __builtin_bit_cast(half8, u);
        const int kkt = mt*2 + kt2;
        #pragma unroll
        for (int nt=0;nt<8;nt++){
          half8 vB = *(const half8*)&Vls[buf][(((kkt*8+nt)*2 + t)*32 + q32)*8];
          O[nt] = MFMA32(pa, vB, O[nt]);
        }
      }
    }

    __syncthreads();   // all readers done with buf; prefetch drained
  }

  // ---- epilogue ----
  lsum += __builtin_bit_cast(float, __shfl_xor(__builtin_bit_cast(int, lsum), 32));
  if (t == 0) Lo[(size_t)b*128 + w*32 + q32] = lsum;

  float* ob = Op + ((size_t)b*128 + w*32)*256;
  #pragma unroll
  for (int nt=0;nt<8;nt++){
    #pragma unroll
    for (int i=0;i<16;i++){
      int row = (i&3) + 8*(i>>2) + 4*t;
      ob[(size_t)row*256 + nt*32 + q32] = O[nt][i];
    }
  }
}

// ---------- cross-block combine of the 4 key-quarters (plain sums) ----------
__global__ void combine4(const float* __restrict__ Op, const float* __restrict__ Lo,
                         float* __restrict__ Out){
  int gid = blockIdx.x*256 + threadIdx.x;   // 524288 threads, one float4 each
  int row = gid >> 6;
  int c4  = (gid & 63) << 2;
  int g   = row >> 7, r = row & 127;

  float lt = 0.f;
  #pragma unroll
  for (int kh=0;kh<4;kh++) lt += Lo[(size_t)(g*4 + kh)*128 + r];
  float li = 1.0f / lt;

  float4 acc = {0,0,0,0};
  #pragma unroll
  for (int kh=0;kh<4;kh++){
    const float4 o = *(const float4*)(Op + ((size_t)(g*4 + kh)*128 + r)*256 + c4);
    acc.x += o.x; acc.y += o.y; acc.z += o.z; acc.w += o.w;
  }
  acc.x *= li; acc.y *= li; acc.z *= li; acc.w *= li;
  *(float4*)(Out + (size_t)row*DS + c4) = acc;
}

extern "C" void kernel_launch(void* const* d_in, const int* in_sizes, int n_in,
                              void* d_out, int out_size, void* d_ws, size_t ws_size,
                              hipStream_t stream){
  (void)in_sizes; (void)n_in; (void)out_size; (void)ws_size;
  const float*   K = (const float*)d_in[0];
  const float*   V = (const float*)d_in[1];
  const float*   Q = (const float*)d_in[2];
  const uint8_t* M = (const uint8_t*)d_in[3];
  float* Out = (float*)d_out;

  _Float16* Kc  = (_Float16*)d_ws;                        // 4 MiB
  _Float16* Vc  = Kc + (size_t)NKS*DS;                    // 4 MiB
  uint32_t* Mp2 = (uint32_t*)(Vc + (size_t)NKS*DS);       // 8 MiB (transposed bitmask)
  float*    Op  = (float*)(Mp2 + (size_t)256*NQS);        // 32 MiB (256 blocks x 128x256)
  float*    Lo  = Op + (size_t)256*128*256;               // 128 KiB
  uint32_t* flag = (uint32_t*)(Lo + 256*128);             // 4 B

  hipLaunchKernelGGL(detect_mask, dim3(1),    dim3(256), 0, stream, (const uint32_t*)M, flag);
  hipLaunchKernelGGL(pack_mask,   dim3(128),  dim3(256), 0, stream, M, flag, Mp2);
  hipLaunchKernelGGL(cvt_k, dim3(1024), dim3(256), 0, stream, K, Kc);
  hipLaunchKernelGGL(cvt_v, dim3(1024), dim3(256), 0, stream, V, Vc);
  hipLaunchKernelGGL(attn_fwd, dim3(256), dim3(256), 0, stream, Q, Kc, Vc, Mp2, Op, Lo);
  hipLaunchKernelGGL(combine4, dim3(2048), dim3(256), 0, stream, Op, Lo, Out);
}

// Round 9
// 523.842 us; speedup vs baseline: 1.0948x; 1.0948x over previous
//
#include <hip/hip_runtime.h>
#include <stdint.h>
#include <stddef.h>

#define NQS 8192
#define NKS 8192
#define DS  256

typedef _Float16 half8 __attribute__((ext_vector_type(8)));
typedef float floatx16 __attribute__((ext_vector_type(16)));

#define MFMA32(A,B,C) __builtin_amdgcn_mfma_f32_32x32x16_f16(A,B,C,0,0,0)

// async global->LDS 16B: dest = wave-uniform base + lane*16
#define GLOAD_LDS16(gp, lp) \
  __builtin_amdgcn_global_load_lds((const __attribute__((address_space(1))) void*)(gp), \
                                   (__attribute__((address_space(3))) void*)(lp), 16, 0, 0)

// tile = 64 keys x 256 d = 16384 _Float16 ELEMENTS (32 KB).
#define TILE_ELEMS 16384

// ---------- mask dtype detection (int32 0/1 words OR to <=1; packed bytes don't) ----------
__global__ void detect_mask(const uint4* __restrict__ M, uint32_t* __restrict__ flag){
  __shared__ uint32_t s[256];
  uint32_t acc = 0;
  for (int i = threadIdx.x; i < 4096; i += 256){   // 64 KB scanned
    uint4 v = M[i];
    acc |= v.x | v.y | v.z | v.w;
  }
  s[threadIdx.x] = acc;
  __syncthreads();
  if (threadIdx.x == 0){
    uint32_t t = 0;
    for (int i = 0; i < 256; i++) t |= s[i];
    *flag = (t > 1u) ? 1u : 0u;   // 1 = bytes (uint8), 0 = int32
  }
}

// ---------- mask bit-pack, TRANSPOSED + parallel: Mp2[word(k/32)][row] ----------
// grid 2048 = 128 row-strips(64) x 16 word-strips(16); thread packs 4 words.
// Writes coalesced over rows (256 B per 64-lane group). No LDS, no barriers.
__global__ void pack_mask(const uint8_t* __restrict__ M8,
                          const uint32_t* __restrict__ flag,
                          uint32_t* __restrict__ Mp2){
  const int tid  = threadIdx.x;
  const int bgr  = blockIdx.x >> 4;          // row strip
  const int bgw  = blockIdx.x & 15;          // word strip
  const int r    = (bgr << 6) + (tid & 63);  // global row
  const int wl   = tid >> 6;                 // 0..3
  const bool by  = (*flag != 0u);
  #pragma unroll
  for (int i = 0; i < 4; ++i){
    const int w = (bgw << 4) + i*4 + wl;     // global word 0..255
    uint32_t word = 0;
    if (by){
      const uint4* p = (const uint4*)(M8 + (size_t)r*8192 + w*32);
      uint4 a = p[0], b = p[1];
      uint32_t v[8] = {a.x,a.y,a.z,a.w,b.x,b.y,b.z,b.w};
      #pragma unroll
      for (int q=0;q<8;q++){
        word |= (((v[q]      ) & 0xFFu) ? 1u:0u) << (q*4+0);
        word |= (((v[q] >>  8) & 0xFFu) ? 1u:0u) << (q*4+1);
        word |= (((v[q] >> 16) & 0xFFu) ? 1u:0u) << (q*4+2);
        word |= (((v[q] >> 24)        ) ? 1u:0u) << (q*4+3);
      }
    } else {
      const uint4* p = (const uint4*)M8 + (size_t)r*2048 + w*8;
      #pragma unroll
      for (int q=0;q<8;q++){
        uint4 v = p[q];
        word |= (v.x?1u:0u) << (q*4+0);
        word |= (v.y?1u:0u) << (q*4+1);
        word |= (v.z?1u:0u) << (q*4+2);
        word |= (v.w?1u:0u) << (q*4+3);
      }
    }
    Mp2[(size_t)w*NQS + r] = word;
  }
}

// ---------- fused K/V conversion into tiled 32x32x16 operand layouts ----------
// blocks 0..1023: K[key][d] -> tile(key>>6) offset (((mt*16+kt)*2+t)*32+k32)*8+j
//   (mt=(key>>5)&1, k32=key&31, kt=d>>4, t=(d>>3)&1, j=d&7)
// blocks 1024..2047: V[key][d] -> tile offset (((kkt*8+nt)*2+t)*32+d32)*8+j
//   (kkt=(key>>4)&3, t=(key>>3)&1, j=key&7, nt=d>>5, d32=d&31)
__global__ void cvt_kv(const float* __restrict__ K, const float* __restrict__ V,
                       _Float16* __restrict__ Kc, _Float16* __restrict__ Vc){
  if (blockIdx.x < 1024){
    int gid = blockIdx.x*256 + threadIdx.x;      // 262144
    int key = gid & 8191;
    int c   = gid >> 13;                         // 0..31
    int kt = c >> 1, t = c & 1;
    const float4* s = (const float4*)(K + (size_t)key*DS + kt*16 + t*8);
    float4 x = s[0], y = s[1];
    half8 h = {(_Float16)x.x,(_Float16)x.y,(_Float16)x.z,(_Float16)x.w,
               (_Float16)y.x,(_Float16)y.y,(_Float16)y.z,(_Float16)y.w};
    int tile = key >> 6, mt = (key >> 5) & 1, k32 = key & 31;
    size_t off = (size_t)tile*TILE_ELEMS + (((mt*16 + kt)*2 + t)*32 + k32)*8;
    *(half8*)(Kc + off) = h;
  } else {
    int gid = (blockIdx.x - 1024)*256 + threadIdx.x;  // 262144
    int d32 = gid & 31;
    int t   = (gid >> 5) & 1;
    int nt  = (gid >> 6) & 7;
    int kkt = (gid >> 9) & 3;
    int tile = gid >> 11;
    int d = nt*32 + d32;
    int kb8 = tile*64 + kkt*16 + t*8;
    half8 h;
    #pragma unroll
    for (int j=0;j<8;j++) h[j] = (_Float16)V[(size_t)(kb8 + j)*DS + d];
    *(half8*)(Vc + (size_t)gid*8) = h;
  }
}

// ---------- main flash kernel: 32x32x16 MFMA, S^T trick, no P LDS round-trip ----------
// grid 256 = 64 row-groups(128) x 4 key-quarters, 1 block/CU (128 KB LDS).
// Wave w owns 32 queries (q = lane&31). S^T = K·Q^T: A=K (LDS), B=Q (regs).
// P exits in C-layout (q=lane&31) == PV A-operand m-index; only a shfl_xor(32)
// half-wave exchange for the key dimension. Fixed-max softmax (shift-invariant).
__global__ __launch_bounds__(256, 1) void attn_fwd(
  const float* __restrict__ Qf, const _Float16* __restrict__ Kc,
  const _Float16* __restrict__ Vc, const uint32_t* __restrict__ Mp2,
  float* __restrict__ Op, float* __restrict__ Lo)
{
  __shared__ _Float16 Kls[2][16384];   // [buf] 32 KB: [(mt*16+kt)*2+t][key32][8]
  __shared__ _Float16 Vls[2][16384];   // [buf] 32 KB: [((kkt*8+nt)*2+t)][d32][8]

  const int tid  = threadIdx.x;
  const int w    = tid >> 6;
  const int lane = tid & 63;
  const int q32  = lane & 31;
  const int t    = lane >> 5;
  const int b    = blockIdx.x;
  const int g128 = b >> 2;
  const int kh   = b & 3;
  const int rowbase = (g128 << 7) + w*32;
  const int kbase   = kh << 11;
  const int tile0   = kbase >> 6;
  const int kw0     = kbase >> 5;

  const float kLog = 0.09016844005556021f;  // (1/16) * log2(e)
  const float MFIX = 6.0f;

  // Q B-frags: n=lane&31, k=(lane>>5)*8+j
  half8 qf[16];
  {
    const float* qrow = Qf + (size_t)(rowbase + q32)*DS;
    #pragma unroll
    for (int kt=0;kt<16;kt++){
      const float4* s = (const float4*)(qrow + kt*16 + t*8);
      float4 x = s[0], y = s[1];
      qf[kt] = (half8){(_Float16)x.x,(_Float16)x.y,(_Float16)x.z,(_Float16)x.w,
                       (_Float16)y.x,(_Float16)y.y,(_Float16)y.z,(_Float16)y.w};
    }
  }

  floatx16 O[8];
  #pragma unroll
  for (int nt=0;nt<8;nt++)
    #pragma unroll
    for (int i=0;i<16;i++) O[nt][i] = 0.f;
  float lsum = 0.f;

  // ---- stage tile 0 ----
  #pragma unroll
  for (int j=0;j<8;j++){
    int c = w*8 + j;
    GLOAD_LDS16(Kc + (size_t)tile0*TILE_ELEMS + c*512 + lane*8, &Kls[0][c*512]);
    GLOAD_LDS16(Vc + (size_t)tile0*TILE_ELEMS + c*512 + lane*8, &Vls[0][c*512]);
  }
  __syncthreads();

  #pragma unroll 1
  for (int it=0; it<32; ++it){
    const int buf = it & 1;

    if (it < 31){
      const size_t tb = (size_t)(tile0 + it + 1)*TILE_ELEMS;
      #pragma unroll
      for (int j=0;j<8;j++){
        int c = w*8 + j;
        GLOAD_LDS16(Kc + tb + c*512 + lane*8, &Kls[buf^1][c*512]);
        GLOAD_LDS16(Vc + tb + c*512 + lane*8, &Vls[buf^1][c*512]);
      }
    }

    #pragma unroll
    for (int mt=0; mt<2; ++mt){
      const uint32_t mw = Mp2[(size_t)(kw0 + it*2 + mt)*NQS + rowbase + q32];

      // ---- S^T[key32][q32], two 8-deep chains ----
      floatx16 S0, S1;
      #pragma unroll
      for (int i=0;i<16;i++){ S0[i]=0.f; S1[i]=0.f; }
      #pragma unroll
      for (int kt=0;kt<8;kt++){
        half8 kA = *(const half8*)&Kls[buf][(((mt*16+kt)*2 + t)*32 + q32)*8];
        S0 = MFMA32(kA, qf[kt], S0);
      }
      #pragma unroll
      for (int kt=8;kt<16;kt++){
        half8 kA = *(const half8*)&Kls[buf][(((mt*16+kt)*2 + t)*32 + q32)*8];
        S1 = MFMA32(kA, qf[kt], S1);
      }

      // ---- p = exp2(S*kLog - MFIX) masked; pack to f16x2 by s-group ----
      uint32_t pk[4][2];
      #pragma unroll
      for (int s=0;s<4;s++){
        float pv[4];
        #pragma unroll
        for (int rr=0;rr<4;rr++){
          int i = s*4 + rr;
          int keybit = rr + 8*s + 4*t;          // key within 32-group (C-row decode)
          float e = __builtin_amdgcn_exp2f(__builtin_fmaf(S0[i]+S1[i], kLog, -MFIX));
          float p = ((mw >> keybit) & 1u) ? e : 0.f;
          lsum += p;
          pv[rr] = p;
        }
        pk[s][0] = __builtin_bit_cast(uint32_t, __builtin_amdgcn_cvt_pkrtz(pv[0], pv[1]));
        pk[s][1] = __builtin_bit_cast(uint32_t, __builtin_amdgcn_cvt_pkrtz(pv[2], pv[3]));
      }

      // ---- PV: per 16-key k-tile, assemble A-frag via half-wave exchange ----
      #pragma unroll
      for (int kt2=0; kt2<2; ++kt2){
        const int s_own  = kt2*2 + t;
        const int s_send = kt2*2 + (t^1);
        uint32_t r0 = __shfl_xor(__builtin_bit_cast(int, pk[s_send][0]), 32);
        uint32_t r1 = __shfl_xor(__builtin_bit_cast(int, pk[s_send][1]), 32);
        uint32_t lo0 = (t==0) ? pk[s_own][0] : r0;
        uint32_t lo1 = (t==0) ? pk[s_own][1] : r1;
        uint32_t hi0 = (t==0) ? r0 : pk[s_own][0];
        uint32_t hi1 = (t==0) ? r1 : pk[s_own][1];
        uint4 u = {lo0, lo1, hi0, hi1};
        half8 pa = __builtin_bit_cast(half8, u);
        const int kkt = mt*2 + kt2;
        #pragma unroll
        for (int nt=0;nt<8;nt++){
          half8 vB = *(const half8*)&Vls[buf][(((kkt*8+nt)*2 + t)*32 + q32)*8];
          O[nt] = MFMA32(pa, vB, O[nt]);
        }
      }
    }

    __syncthreads();   // readers done with buf; prefetch drained
  }

  // ---- epilogue ----
  lsum += __builtin_bit_cast(float, __shfl_xor(__builtin_bit_cast(int, lsum), 32));
  if (t == 0) Lo[(size_t)b*128 + w*32 + q32] = lsum;

  float* ob = Op + ((size_t)b*128 + w*32)*256;
  #pragma unroll
  for (int nt=0;nt<8;nt++){
    #pragma unroll
    for (int i=0;i<16;i++){
      int row = (i&3) + 8*(i>>2) + 4*t;
      ob[(size_t)row*256 + nt*32 + q32] = O[nt][i];
    }
  }
}

// ---------- cross-block combine of the 4 key-quarters (plain sums) ----------
__global__ void combine4(const float* __restrict__ Op, const float* __restrict__ Lo,
                         float* __restrict__ Out){
  int gid = blockIdx.x*256 + threadIdx.x;   // 524288 threads, one float4 each
  int row = gid >> 6;
  int c4  = (gid & 63) << 2;
  int g   = row >> 7, r = row & 127;

  float lt = 0.f;
  #pragma unroll
  for (int kh=0;kh<4;kh++) lt += Lo[(size_t)(g*4 + kh)*128 + r];
  float li = 1.0f / lt;

  float4 acc = {0,0,0,0};
  #pragma unroll
  for (int kh=0;kh<4;kh++){
    const float4 o = *(const float4*)(Op + ((size_t)(g*4 + kh)*128 + r)*256 + c4);
    acc.x += o.x; acc.y += o.y; acc.z += o.z; acc.w += o.w;
  }
  acc.x *= li; acc.y *= li; acc.z *= li; acc.w *= li;
  *(float4*)(Out + (size_t)row*DS + c4) = acc;
}

extern "C" void kernel_launch(void* const* d_in, const int* in_sizes, int n_in,
                              void* d_out, int out_size, void* d_ws, size_t ws_size,
                              hipStream_t stream){
  (void)in_sizes; (void)n_in; (void)out_size; (void)ws_size;
  const float*   K = (const float*)d_in[0];
  const float*   V = (const float*)d_in[1];
  const float*   Q = (const float*)d_in[2];
  const uint8_t* M = (const uint8_t*)d_in[3];
  float* Out = (float*)d_out;

  _Float16* Kc  = (_Float16*)d_ws;                        // 4 MiB
  _Float16* Vc  = Kc + (size_t)NKS*DS;                    // 4 MiB
  uint32_t* Mp2 = (uint32_t*)(Vc + (size_t)NKS*DS);       // 8 MiB (transposed bitmask)
  float*    Op  = (float*)(Mp2 + (size_t)256*NQS);        // 32 MiB (256 blocks x 128x256)
  float*    Lo  = Op + (size_t)256*128*256;               // 128 KiB
  uint32_t* flag = (uint32_t*)(Lo + 256*128);             // 4 B

  hipLaunchKernelGGL(detect_mask, dim3(1),    dim3(256), 0, stream, (const uint4*)M, flag);
  hipLaunchKernelGGL(pack_mask,   dim3(2048), dim3(256), 0, stream, M, flag, Mp2);
  hipLaunchKernelGGL(cvt_kv, dim3(2048), dim3(256), 0, stream, K, V, Kc, Vc);
  hipLaunchKernelGGL(attn_fwd, dim3(256), dim3(256), 0, stream, Q, Kc, Vc, Mp2, Op, Lo);
  hipLaunchKernelGGL(combine4, dim3(2048), dim3(256), 0, stream, Op, Lo, Out);
}